// Round 8
// baseline (99.941 us; speedup 1.0000x reference)
//
#include <hip/hip_runtime.h>

#define N_PTS 32768
#define M_Q   8192
#define C_F   256
#define PS    4                  // point-range splits
#define RNG   (N_PTS / PS)       // 8192 points per block
#define QW    8                  // queries per wave
#define NW    4                  // waves per block
#define QBL   (QW * NW)          // 32 queries per block
#define NSL   2                  // chunk slots (4096 pts each); sub-chunk = 64 pts
#define NQB   (M_Q / QBL)        // 256 query blocks per side
#define MU    1e-3f              // rigorous e-vs-(d*-a2) pruning margin

__device__ __forceinline__ float rn_mul(float a, float b) { return __fmul_rn(a, b); }
__device__ __forceinline__ float rn_add(float a, float b) { return __fadd_rn(a, b); }
__device__ __forceinline__ float rfl(float x) {
    return __int_as_float(__builtin_amdgcn_readfirstlane(__float_as_int(x)));
}

// exact lexicographic (d,i) insert into running top-2 pair
__device__ __forceinline__ void ins_lex(float d, int i, float& b1, int& j1,
                                        float& b2, int& j2) {
    bool lt1 = (d < b1) || (d == b1 && i < j1);
    bool lt2 = (d < b2) || (d == b2 && i < j2);
    b2 = lt1 ? b1 : (lt2 ? d : b2);
    j2 = lt1 ? j1 : (lt2 ? i : j2);
    b1 = lt1 ? d : b1;
    j1 = lt1 ? i : j1;
}

// merge two value-pairs (each a1<=a2) -> two smallest overall
__device__ __forceinline__ void vpair_merge(float& a1, float& a2, float b1, float b2) {
    float n1 = fminf(a1, b1);
    float n2 = fminf(fmaxf(a1, b1), fminf(a2, b2));
    a1 = n1; a2 = n2;
}

// Pack [-2x, -2y, -2z, b2] per point for both sides into workspace.
// b2 computed from ORIGINAL coords exactly as numpy: (x*x + y*y) + z*z.
__global__ __launch_bounds__(256) void pack_pts(const float* __restrict__ c0,
                                                const float* __restrict__ c1,
                                                float4* __restrict__ pts) {
    int t = blockIdx.x * blockDim.x + threadIdx.x;   // 0 .. 2N-1
    int side = t >> 15;
    int n = t & (N_PTS - 1);
    const float* c = side ? c1 : c0;
    float x = c[n * 3 + 0], y = c[n * 3 + 1], z = c[n * 3 + 2];
    float b2 = rn_add(rn_add(rn_mul(x, x), rn_mul(y, y)), rn_mul(z, z));
    pts[t] = make_float4(-2.0f * x, -2.0f * y, -2.0f * z, b2);  // *2 exact
}

// Pass 1: branchless e-space sub-chunk minima (3 FMA + min per pair).
// Pass 2: exact-numpy rescan of surviving 64-pt sub-chunks, lex top-2.
__global__ __launch_bounds__(256) void pool_scan(
    const float* __restrict__ sc0, const float* __restrict__ sc1,
    const float4* __restrict__ pts, int4* __restrict__ part)
{
    int bid  = blockIdx.x;            // 2 * NQB * PS = 2048
    int side = bid >> 10;
    int r    = bid & 1023;
    int qblk = r >> 2;                // 0..255
    int ps   = r & (PS - 1);          // 0..3
    const float* sc = side ? sc1 : sc0;

    int tid  = threadIdx.x;
    int wave = tid >> 6;
    int lane = tid & 63;
    int q0   = qblk * QBL + wave * QW;
    const float4* Pg = pts + (size_t)side * N_PTS + ps * RNG;

    // wave-uniform query scalars (SGPR via readfirstlane)
    float ax[QW], ay[QW], az[QW], a2[QW];
#pragma unroll
    for (int q = 0; q < QW; ++q) {
        int qq = q0 + q;
        float x = rfl(sc[qq * 3 + 0]);
        float y = rfl(sc[qq * 3 + 1]);
        float z = rfl(sc[qq * 3 + 2]);
        ax[q] = x; ay[q] = y; az[q] = z;
        a2[q] = rn_add(rn_add(rn_mul(x, x), rn_mul(y, y)), rn_mul(z, z));
    }

    float m[NSL][QW];
#pragma unroll
    for (int s = 0; s < NSL; ++s)
#pragma unroll
        for (int q = 0; q < QW; ++q) m[s][q] = __int_as_float(0x7f800000);

    // ---- Pass 1: stream 8192 pts straight from global (L2-resident) ----
#pragma unroll
    for (int s = 0; s < NSL; ++s) {
#pragma unroll 8
        for (int j = 0; j < 64; ++j) {
            float4 pt = Pg[s * 4096 + j * 64 + lane];
#pragma unroll
            for (int q = 0; q < QW; ++q) {
                // e = b2 - 2*dot via premultiplied coords: 3 FMA
                float e = __builtin_fmaf(az[q], pt.z,
                           __builtin_fmaf(ay[q], pt.y,
                            __builtin_fmaf(ax[q], pt.x, pt.w)));
                m[s][q] = fminf(m[s][q], e);
            }
        }
    }

    // ---- beta per query: 2nd-smallest sub-chunk min over this range ----
    float beta[QW];
#pragma unroll
    for (int q = 0; q < QW; ++q) {
        float p1 = fminf(m[0][q], m[1][q]);
        float p2 = fmaxf(m[0][q], m[1][q]);
#pragma unroll
        for (int off = 1; off < 64; off <<= 1) {
            float o1 = __shfl_xor(p1, off);
            float o2 = __shfl_xor(p2, off);
            vpair_merge(p1, p2, o1, o2);
        }
        beta[q] = p2 + MU;
    }

    // ---- Pass 2: exact rescan of surviving sub-chunks ----
    float D1[QW], D2[QW];
    int   I1[QW], I2[QW];
#pragma unroll
    for (int q = 0; q < QW; ++q) {
        D1[q] = __int_as_float(0x7f800000); D2[q] = D1[q];
        I1[q] = 0x7fffffff; I2[q] = 0x7fffffff;
    }
#pragma unroll
    for (int s = 0; s < NSL; ++s) {
#pragma unroll
        for (int q = 0; q < QW; ++q) {
            unsigned long long fm = __ballot(m[s][q] <= beta[q]);
            while (fm) {                       // ~2 fires per (q)
                int l = (int)__builtin_ctzll(fm);
                fm &= fm - 1;
                int rel = s * 4096 + lane * 64 + l;  // lane j rescans pt j
                float4 p = Pg[rel];
                float x = -0.5f * p.x, y = -0.5f * p.y, z = -0.5f * p.z; // exact
                float dot = __builtin_fmaf(az[q], z,
                             __builtin_fmaf(ay[q], y, rn_mul(ax[q], x)));
                float dd = __builtin_fmaf(-2.0f, dot, rn_add(a2[q], p.w));
                ins_lex(dd, ps * RNG + rel, D1[q], I1[q], D2[q], I2[q]);
            }
        }
    }

    // butterfly lex-merge across 64 lanes
#pragma unroll
    for (int off = 1; off < 64; off <<= 1) {
#pragma unroll
        for (int q = 0; q < QW; ++q) {
            float od1 = __shfl_xor(D1[q], off); int oi1 = __shfl_xor(I1[q], off);
            float od2 = __shfl_xor(D2[q], off); int oi2 = __shfl_xor(I2[q], off);
            ins_lex(od1, oi1, D1[q], I1[q], D2[q], I2[q]);
            ins_lex(od2, oi2, D1[q], I1[q], D2[q], I2[q]);
        }
    }
    if (lane == 0) {
#pragma unroll
        for (int q = 0; q < QW; ++q) {
            int qg = side * M_Q + q0 + q;
            part[qg * PS + ps] = make_int4(__float_as_int(D1[q]), I1[q],
                                           __float_as_int(D2[q]), I2[q]);
        }
    }
}

// Merge the PS partials per query (exact lex), gather feature rows.
__global__ __launch_bounds__(256) void merge_gather(
    const float* __restrict__ src, const float* __restrict__ tgt,
    const int4* __restrict__ part, float* __restrict__ out)
{
    __shared__ int sidx[8];

    int bid  = blockIdx.x;            // 2 * M_Q/8 = 2048
    int side = bid >> 10;
    int qb   = bid & 1023;
    const float* feats = side ? tgt : src;
    int tid = threadIdx.x;
    int q0  = qb * 8;

    if (tid < 8) {
        int qg = side * M_Q + q0 + tid;
        int4 p0 = part[qg * PS + 0];
        float b1 = __int_as_float(p0.x), b2 = __int_as_float(p0.z);
        int   j1 = p0.y,                 j2 = p0.w;
#pragma unroll
        for (int sp = 1; sp < PS; ++sp) {
            int4 p = part[qg * PS + sp];
            ins_lex(__int_as_float(p.x), p.y, b1, j1, b2, j2);
            ins_lex(__int_as_float(p.z), p.w, b1, j1, b2, j2);
        }
        sidx[tid] = j2;
    }
    __syncthreads();

    // gather: 8 rows of 256 floats; 32 threads per row, 2 float4 each
    int qi = tid >> 5;
    int cj = tid & 31;
    int row = sidx[qi];
    const float4* sp = (const float4*)(feats + (size_t)row * C_F);
    float4* dp = (float4*)(out + ((size_t)side * M_Q + q0 + qi) * (size_t)C_F);
    dp[cj]      = sp[cj];
    dp[cj + 32] = sp[cj + 32];
}

extern "C" void kernel_launch(void* const* d_in, const int* in_sizes, int n_in,
                              void* d_out, int out_size, void* d_ws, size_t ws_size,
                              hipStream_t stream) {
    const float* src  = (const float*)d_in[0];
    const float* tgt  = (const float*)d_in[1];
    const float* c0   = (const float*)d_in[2];  // src_coords   (N,3)
    const float* c1   = (const float*)d_in[3];  // tgt_coords   (N,3)
    const float* sh0  = (const float*)d_in[4];  // src_shortcut (M,3)
    const float* sh1  = (const float*)d_in[5];  // tgt_shortcut (M,3)
    float* out = (float*)d_out;

    float4* pts  = (float4*)d_ws;                                   // 1 MB
    int4*   part = (int4*)((char*)d_ws + (size_t)2 * N_PTS * sizeof(float4)); // 2 MB

    hipLaunchKernelGGL(pack_pts, dim3(2 * N_PTS / 256), dim3(256), 0, stream,
                       c0, c1, pts);
    hipLaunchKernelGGL(pool_scan, dim3(2 * NQB * PS), dim3(256), 0, stream,
                       sh0, sh1, pts, part);
    hipLaunchKernelGGL(merge_gather, dim3(2 * (M_Q / 8)), dim3(256), 0, stream,
                       src, tgt, part, out);
}